// Round 1
// baseline (1084.262 us; speedup 1.0000x reference)
//
#include <hip/hip_runtime.h>
#include <hip/hip_bf16.h>

// ---- problem constants (match reference) ----
#define BB 2048
#define NN 64
#define DD 64
#define HH 256
#define L_HAND 16
#define L_UNIT 8
#define L_CE 8
#define L_SK 8
#define L_VS 16
#define L_ME 16
#define L_TGT 8
#define STATE_SC 64
#define CE_SC 8
#define SITE_SC 6
#define ME_SC 8
#define ACT_SC 16
#define STATE_IN 662
#define ACT_IN 464

#define ROWS_A 4   // batch rows per block in state kernel
#define TM 16      // action rows per block in action kernel

// ===================== state encoding kernel =====================
// grid: BB/ROWS_A blocks, 256 threads.
// Computes state_repr = tanh(state_input @ W_s + b_s), then
//   s_part[b,:] = state_repr @ W1[:256,:]   (state half of scoring GEMM)
//   value[b]    = state_repr @ W_v + b_v
__global__ __launch_bounds__(256) void state_kernel(
    const float* __restrict__ state_scalars,
    const int* __restrict__ mode_id, const int* __restrict__ terrain_id,
    const int* __restrict__ site_type_id,
    const int* __restrict__ hand_ids, const int* __restrict__ hand_mask,
    const int* __restrict__ unit_ids, const int* __restrict__ unit_mask,
    const int* __restrict__ ce_ids, const float* __restrict__ ce_sc, const int* __restrict__ ce_mask,
    const int* __restrict__ skill_ids, const int* __restrict__ skill_mask,
    const int* __restrict__ vs_ids, const float* __restrict__ vs_sc, const int* __restrict__ vs_mask,
    const int* __restrict__ me_ids, const float* __restrict__ me_sc, const int* __restrict__ me_mask,
    const float* __restrict__ card_emb, const float* __restrict__ unit_emb,
    const float* __restrict__ enemy_emb, const float* __restrict__ mode_emb,
    const float* __restrict__ ter_emb, const float* __restrict__ site_emb,
    const float* __restrict__ skill_emb, const float* __restrict__ msite_emb,
    const float* __restrict__ W_s, const float* __restrict__ b_s,
    const float* __restrict__ W1, const float* __restrict__ W_v, const float* __restrict__ b_v,
    float* __restrict__ s_part, float* __restrict__ out_value)
{
    __shared__ float s_in[ROWS_A][STATE_IN];
    __shared__ float s_repr[ROWS_A][HH];
    __shared__ float s_red[ROWS_A][4];

    const int t = threadIdx.x;
    const int b0 = blockIdx.x * ROWS_A;

    // ---- build state_input rows in LDS ----
    for (int r = 0; r < ROWS_A; ++r) {
        const int b = b0 + r;
        for (int o = t; o < STATE_IN; o += 256) {
            float v;
            if (o < 64) {
                v = state_scalars[b * STATE_SC + o];
            } else if (o < 128) {
                v = mode_emb[mode_id[b] * DD + (o - 64)];
            } else if (o < 192) {           // hand_pool
                const int d = o - 128; float s = 0.f; int c = 0;
                for (int l = 0; l < L_HAND; ++l) {
                    const int m = hand_mask[b * L_HAND + l]; c += m;
                    if (m) s += card_emb[hand_ids[b * L_HAND + l] * DD + d];
                }
                v = s / (float)(c > 1 ? c : 1);
            } else if (o < 256) {           // unit_pool
                const int d = o - 192; float s = 0.f; int c = 0;
                for (int l = 0; l < L_UNIT; ++l) {
                    const int m = unit_mask[b * L_UNIT + l]; c += m;
                    if (m) s += unit_emb[unit_ids[b * L_UNIT + l] * DD + d];
                }
                v = s / (float)(c > 1 ? c : 1);
            } else if (o < 320) {
                v = ter_emb[terrain_id[b] * DD + (o - 256)];
            } else if (o < 384) {
                v = site_emb[site_type_id[b] * DD + (o - 320)];
            } else if (o < 456) {           // ce_pool (64 emb + 8 scalars)
                const int d = o - 384; float s = 0.f; int c = 0;
                for (int l = 0; l < L_CE; ++l) {
                    const int m = ce_mask[b * L_CE + l]; c += m;
                    if (m) s += (d < 64) ? enemy_emb[ce_ids[b * L_CE + l] * DD + d]
                                         : ce_sc[(b * L_CE + l) * CE_SC + (d - 64)];
                }
                v = s / (float)(c > 1 ? c : 1);
            } else if (o < 520) {           // skill_pool
                const int d = o - 456; float s = 0.f; int c = 0;
                for (int l = 0; l < L_SK; ++l) {
                    const int m = skill_mask[b * L_SK + l]; c += m;
                    if (m) s += skill_emb[skill_ids[b * L_SK + l] * DD + d];
                }
                v = s / (float)(c > 1 ? c : 1);
            } else if (o < 590) {           // vs_pool (64 emb + 6 scalars)
                const int d = o - 520; float s = 0.f; int c = 0;
                for (int l = 0; l < L_VS; ++l) {
                    const int m = vs_mask[b * L_VS + l]; c += m;
                    if (m) s += (d < 64) ? msite_emb[vs_ids[b * L_VS + l] * DD + d]
                                         : vs_sc[(b * L_VS + l) * SITE_SC + (d - 64)];
                }
                v = s / (float)(c > 1 ? c : 1);
            } else {                        // me_pool (64 emb + 8 scalars)
                const int d = o - 590; float s = 0.f; int c = 0;
                for (int l = 0; l < L_ME; ++l) {
                    const int m = me_mask[b * L_ME + l]; c += m;
                    if (m) s += (d < 64) ? enemy_emb[me_ids[b * L_ME + l] * DD + d]
                                         : me_sc[(b * L_ME + l) * ME_SC + (d - 64)];
                }
                v = s / (float)(c > 1 ? c : 1);
            }
            s_in[r][o] = v;
        }
    }
    __syncthreads();

    // ---- state_repr = tanh(s_in @ W_s + b_s), thread t owns column t ----
    float acc[ROWS_A];
#pragma unroll
    for (int r = 0; r < ROWS_A; ++r) acc[r] = b_s[t];
    for (int k = 0; k < STATE_IN; k += 2) {     // 662 is even
        const float w0 = W_s[k * HH + t];
        const float w1 = W_s[(k + 1) * HH + t];
#pragma unroll
        for (int r = 0; r < ROWS_A; ++r) {
            const float2 a = *(const float2*)&s_in[r][k];
            acc[r] = fmaf(a.y, w1, fmaf(a.x, w0, acc[r]));
        }
    }
#pragma unroll
    for (int r = 0; r < ROWS_A; ++r) {
        acc[r] = tanhf(acc[r]);
        s_repr[r][t] = acc[r];
    }

    // ---- value head (reduce over columns) ----
    const float wv = W_v[t];
    const int lane = t & 63, wid = t >> 6;
#pragma unroll
    for (int r = 0; r < ROWS_A; ++r) {
        float v = acc[r] * wv;
        for (int off = 32; off; off >>= 1) v += __shfl_down(v, off);
        if (lane == 0) s_red[r][wid] = v;
    }
    __syncthreads();
    if (t < ROWS_A) {
        out_value[b0 + t] = s_red[t][0] + s_red[t][1] + s_red[t][2] + s_red[t][3] + b_v[0];
    }

    // ---- s_part = state_repr @ W1[:256,:] ----
    float acc2[ROWS_A];
#pragma unroll
    for (int r = 0; r < ROWS_A; ++r) acc2[r] = 0.f;
    for (int k = 0; k < HH; k += 2) {
        const float w0 = W1[k * HH + t];
        const float w1 = W1[(k + 1) * HH + t];
#pragma unroll
        for (int r = 0; r < ROWS_A; ++r) {
            const float2 a = *(const float2*)&s_repr[r][k];
            acc2[r] = fmaf(a.y, w1, fmaf(a.x, w0, acc2[r]));
        }
    }
#pragma unroll
    for (int r = 0; r < ROWS_A; ++r) s_part[(b0 + r) * HH + t] = acc2[r];
}

// ===================== action encode + score kernel =====================
// grid: (BB*NN)/TM blocks, 256 threads. Each block: one batch row b, TM actions.
__global__ __launch_bounds__(256) void action_kernel(
    const int* __restrict__ action_ids, const float* __restrict__ action_scalars,
    const int* __restrict__ tgt_ids, const int* __restrict__ tgt_mask,
    const float* __restrict__ at_emb, const float* __restrict__ src_emb,
    const float* __restrict__ card_emb, const float* __restrict__ unit_emb,
    const float* __restrict__ enemy_emb, const float* __restrict__ skill_emb,
    const float* __restrict__ W_a, const float* __restrict__ b_a,
    const float* __restrict__ W1, const float* __restrict__ b1,
    const float* __restrict__ W2, const float* __restrict__ b2,
    const float* __restrict__ s_part, float* __restrict__ out_logits)
{
    __shared__ float s_a[TM][ACT_IN];
    __shared__ float s_r[TM][HH];
    __shared__ float s_red[TM][4];

    const int t = threadIdx.x;
    const int bid = blockIdx.x;
    const int b = bid / (NN / TM);
    const int n0 = (bid % (NN / TM)) * TM;

    // ---- build TM action_input rows in LDS ----
    for (int r = 0; r < TM; ++r) {
        const int an = b * NN + n0 + r;
        const int* ids = &action_ids[an * 6];
        for (int o = t; o < ACT_IN; o += 256) {
            float v;
            if (o < 64)       v = at_emb[ids[0] * DD + o];
            else if (o < 128) v = src_emb[ids[1] * DD + (o - 64)];
            else if (o < 192) v = card_emb[ids[2] * DD + (o - 128)];
            else if (o < 256) v = unit_emb[ids[3] * DD + (o - 192)];
            else if (o < 320) v = enemy_emb[ids[4] * DD + (o - 256)];
            else if (o < 384) v = skill_emb[ids[5] * DD + (o - 320)];
            else if (o < 448) {             // tgt_pool
                const int d = o - 384; float s = 0.f; int c = 0;
                for (int l = 0; l < L_TGT; ++l) {
                    const int m = tgt_mask[an * L_TGT + l]; c += m;
                    if (m) s += enemy_emb[tgt_ids[an * L_TGT + l] * DD + d];
                }
                v = s / (float)(c > 1 ? c : 1);
            } else {
                v = action_scalars[an * ACT_SC + (o - 448)];
            }
            s_a[r][o] = v;
        }
    }
    __syncthreads();

    // ---- GEMM1: action_repr = tanh(a_in @ W_a + b_a); thread t owns column t ----
    float acc[TM];
#pragma unroll
    for (int r = 0; r < TM; ++r) acc[r] = b_a[t];
    for (int k = 0; k < ACT_IN; k += 4) {
        const float w0 = W_a[(k + 0) * HH + t];
        const float w1 = W_a[(k + 1) * HH + t];
        const float w2 = W_a[(k + 2) * HH + t];
        const float w3 = W_a[(k + 3) * HH + t];
#pragma unroll
        for (int r = 0; r < TM; ++r) {
            const float4 a = *(const float4*)&s_a[r][k];
            acc[r] = fmaf(a.w, w3, fmaf(a.z, w2, fmaf(a.y, w1, fmaf(a.x, w0, acc[r]))));
        }
    }
#pragma unroll
    for (int r = 0; r < TM; ++r) s_r[r][t] = tanhf(acc[r]);
    __syncthreads();

    // ---- GEMM2: hidden = tanh(s_part[b] + b1 + action_repr @ W1[256:,:]) ----
    const float sp = s_part[b * HH + t] + b1[t];
#pragma unroll
    for (int r = 0; r < TM; ++r) acc[r] = sp;
    const float* W1b = W1 + 256 * HH;   // action half of W1
    for (int k = 0; k < HH; k += 4) {
        const float w0 = W1b[(k + 0) * HH + t];
        const float w1 = W1b[(k + 1) * HH + t];
        const float w2 = W1b[(k + 2) * HH + t];
        const float w3 = W1b[(k + 3) * HH + t];
#pragma unroll
        for (int r = 0; r < TM; ++r) {
            const float4 a = *(const float4*)&s_r[r][k];
            acc[r] = fmaf(a.w, w3, fmaf(a.z, w2, fmaf(a.y, w1, fmaf(a.x, w0, acc[r]))));
        }
    }

    // ---- logits: reduce tanh(hidden) * W2 over columns ----
    const float w2c = W2[t];
    const int lane = t & 63, wid = t >> 6;
#pragma unroll
    for (int r = 0; r < TM; ++r) {
        float v = tanhf(acc[r]) * w2c;
        for (int off = 32; off; off >>= 1) v += __shfl_down(v, off);
        if (lane == 0) s_red[r][wid] = v;
    }
    __syncthreads();
    if (t < TM) {
        out_logits[b * NN + n0 + t] = s_red[t][0] + s_red[t][1] + s_red[t][2] + s_red[t][3] + b2[0];
    }
}

extern "C" void kernel_launch(void* const* d_in, const int* in_sizes, int n_in,
                              void* d_out, int out_size, void* d_ws, size_t ws_size,
                              hipStream_t stream) {
    const float* state_scalars = (const float*)d_in[0];
    const int*   mode_id       = (const int*)d_in[1];
    const int*   terrain_id    = (const int*)d_in[2];
    const int*   site_type_id  = (const int*)d_in[3];
    const int*   hand_ids      = (const int*)d_in[4];
    const int*   hand_mask     = (const int*)d_in[5];
    const int*   unit_ids      = (const int*)d_in[6];
    const int*   unit_mask     = (const int*)d_in[7];
    const int*   ce_ids        = (const int*)d_in[8];
    const float* ce_sc         = (const float*)d_in[9];
    const int*   ce_mask       = (const int*)d_in[10];
    const int*   skill_ids     = (const int*)d_in[11];
    const int*   skill_mask    = (const int*)d_in[12];
    const int*   vs_ids        = (const int*)d_in[13];
    const float* vs_sc         = (const float*)d_in[14];
    const int*   vs_mask       = (const int*)d_in[15];
    const int*   me_ids        = (const int*)d_in[16];
    const float* me_sc         = (const float*)d_in[17];
    const int*   me_mask       = (const int*)d_in[18];
    const int*   action_ids    = (const int*)d_in[19];
    const float* action_scalars= (const float*)d_in[20];
    const int*   tgt_ids       = (const int*)d_in[21];
    const int*   tgt_mask      = (const int*)d_in[22];
    const float* card_emb      = (const float*)d_in[23];
    const float* unit_emb      = (const float*)d_in[24];
    const float* enemy_emb     = (const float*)d_in[25];
    const float* at_emb        = (const float*)d_in[26];
    const float* src_emb       = (const float*)d_in[27];
    const float* mode_emb      = (const float*)d_in[28];
    const float* ter_emb       = (const float*)d_in[29];
    const float* site_emb      = (const float*)d_in[30];
    const float* skill_emb     = (const float*)d_in[31];
    const float* msite_emb     = (const float*)d_in[32];
    const float* W_s           = (const float*)d_in[33];
    const float* b_s           = (const float*)d_in[34];
    const float* W_a           = (const float*)d_in[35];
    const float* b_a           = (const float*)d_in[36];
    const float* W1            = (const float*)d_in[37];
    const float* b1            = (const float*)d_in[38];
    const float* W2            = (const float*)d_in[39];
    const float* b2            = (const float*)d_in[40];
    const float* W_v           = (const float*)d_in[41];
    const float* b_v           = (const float*)d_in[42];

    float* out_logits = (float*)d_out;                 // [B, N]
    float* out_value  = (float*)d_out + (size_t)BB * NN; // [B]
    float* s_part     = (float*)d_ws;                  // [B, H] floats (2 MB)

    state_kernel<<<BB / ROWS_A, 256, 0, stream>>>(
        state_scalars, mode_id, terrain_id, site_type_id,
        hand_ids, hand_mask, unit_ids, unit_mask,
        ce_ids, ce_sc, ce_mask, skill_ids, skill_mask,
        vs_ids, vs_sc, vs_mask, me_ids, me_sc, me_mask,
        card_emb, unit_emb, enemy_emb, mode_emb, ter_emb, site_emb,
        skill_emb, msite_emb,
        W_s, b_s, W1, W_v, b_v, s_part, out_value);

    action_kernel<<<(BB * NN) / TM, 256, 0, stream>>>(
        action_ids, action_scalars, tgt_ids, tgt_mask,
        at_emb, src_emb, card_emb, unit_emb, enemy_emb, skill_emb,
        W_a, b_a, W1, b1, W2, b2, s_part, out_logits);
}

// Round 2
// 510.617 us; speedup vs baseline: 2.1234x; 2.1234x over previous
//
#include <hip/hip_runtime.h>
#include <hip/hip_bf16.h>

// ---- problem constants (match reference) ----
#define BB 2048
#define NN 64
#define DD 64
#define HH 256
#define L_HAND 16
#define L_UNIT 8
#define L_CE 8
#define L_SK 8
#define L_VS 16
#define L_ME 16
#define L_TGT 8
#define STATE_SC 64
#define CE_SC 8
#define SITE_SC 6
#define ME_SC 8
#define ACT_SC 16
#define STATE_IN 662
#define ACT_IN 464

#define ROWS_A 4   // batch rows per block in state kernel

typedef __attribute__((ext_vector_type(8))) short short8;   // 8 bf16 = 4 VGPRs
typedef __attribute__((ext_vector_type(4))) float f32x4;    // MFMA accum

__device__ __forceinline__ float fast_tanh(float x) {
    // tanh(x) = 1 - 2/(e^{2x}+1); e->inf => 1, e->0 => -1 (no NaN at extremes)
    float e = __expf(2.0f * x);
    return 1.0f - 2.0f / (e + 1.0f);
}

// ===================== weight pre-pack kernel =====================
// Packs W_a (464x256, K-padded to 480) and W1[256:,:] (256x256) into bf16
// MFMA B-fragment layout: [kt][ntile][lane][8] with n=lane&15, k=8*(lane>>4)+e.
__global__ __launch_bounds__(256) void pack_kernel(
    const float* __restrict__ W_a, const float* __restrict__ W1,
    ushort* __restrict__ WaP, ushort* __restrict__ W1bP)
{
    const int idx = blockIdx.x * 256 + threadIdx.x;
    if (idx < 480 * 256) {
        const int k = idx >> 8, n = idx & 255;
        const float v = (k < ACT_IN) ? W_a[k * HH + n] : 0.f;
        __hip_bfloat16 h = __float2bfloat16(v);
        const int pi = (((k >> 5) * 16 + (n >> 4)) * 64 +
                        ((n & 15) + 16 * ((k >> 3) & 3))) * 8 + (k & 7);
        WaP[pi] = *reinterpret_cast<ushort*>(&h);
    } else {
        const int j = idx - 480 * 256;
        if (j < 256 * 256) {
            const int k = j >> 8, n = j & 255;
            const float v = W1[(256 + k) * HH + n];
            __hip_bfloat16 h = __float2bfloat16(v);
            const int pi = (((k >> 5) * 16 + (n >> 4)) * 64 +
                            ((n & 15) + 16 * ((k >> 3) & 3))) * 8 + (k & 7);
            W1bP[pi] = *reinterpret_cast<ushort*>(&h);
        }
    }
}

// ===================== state encoding kernel (fp32, unchanged) =====================
__global__ __launch_bounds__(256) void state_kernel(
    const float* __restrict__ state_scalars,
    const int* __restrict__ mode_id, const int* __restrict__ terrain_id,
    const int* __restrict__ site_type_id,
    const int* __restrict__ hand_ids, const int* __restrict__ hand_mask,
    const int* __restrict__ unit_ids, const int* __restrict__ unit_mask,
    const int* __restrict__ ce_ids, const float* __restrict__ ce_sc, const int* __restrict__ ce_mask,
    const int* __restrict__ skill_ids, const int* __restrict__ skill_mask,
    const int* __restrict__ vs_ids, const float* __restrict__ vs_sc, const int* __restrict__ vs_mask,
    const int* __restrict__ me_ids, const float* __restrict__ me_sc, const int* __restrict__ me_mask,
    const float* __restrict__ card_emb, const float* __restrict__ unit_emb,
    const float* __restrict__ enemy_emb, const float* __restrict__ mode_emb,
    const float* __restrict__ ter_emb, const float* __restrict__ site_emb,
    const float* __restrict__ skill_emb, const float* __restrict__ msite_emb,
    const float* __restrict__ W_s, const float* __restrict__ b_s,
    const float* __restrict__ W1, const float* __restrict__ W_v, const float* __restrict__ b_v,
    float* __restrict__ s_part, float* __restrict__ out_value)
{
    __shared__ float s_in[ROWS_A][STATE_IN];
    __shared__ float s_repr[ROWS_A][HH];
    __shared__ float s_red[ROWS_A][4];

    const int t = threadIdx.x;
    const int b0 = blockIdx.x * ROWS_A;

    for (int r = 0; r < ROWS_A; ++r) {
        const int b = b0 + r;
        for (int o = t; o < STATE_IN; o += 256) {
            float v;
            if (o < 64) {
                v = state_scalars[b * STATE_SC + o];
            } else if (o < 128) {
                v = mode_emb[mode_id[b] * DD + (o - 64)];
            } else if (o < 192) {
                const int d = o - 128; float s = 0.f; int c = 0;
                for (int l = 0; l < L_HAND; ++l) {
                    const int m = hand_mask[b * L_HAND + l]; c += m;
                    if (m) s += card_emb[hand_ids[b * L_HAND + l] * DD + d];
                }
                v = s / (float)(c > 1 ? c : 1);
            } else if (o < 256) {
                const int d = o - 192; float s = 0.f; int c = 0;
                for (int l = 0; l < L_UNIT; ++l) {
                    const int m = unit_mask[b * L_UNIT + l]; c += m;
                    if (m) s += unit_emb[unit_ids[b * L_UNIT + l] * DD + d];
                }
                v = s / (float)(c > 1 ? c : 1);
            } else if (o < 320) {
                v = ter_emb[terrain_id[b] * DD + (o - 256)];
            } else if (o < 384) {
                v = site_emb[site_type_id[b] * DD + (o - 320)];
            } else if (o < 456) {
                const int d = o - 384; float s = 0.f; int c = 0;
                for (int l = 0; l < L_CE; ++l) {
                    const int m = ce_mask[b * L_CE + l]; c += m;
                    if (m) s += (d < 64) ? enemy_emb[ce_ids[b * L_CE + l] * DD + d]
                                         : ce_sc[(b * L_CE + l) * CE_SC + (d - 64)];
                }
                v = s / (float)(c > 1 ? c : 1);
            } else if (o < 520) {
                const int d = o - 456; float s = 0.f; int c = 0;
                for (int l = 0; l < L_SK; ++l) {
                    const int m = skill_mask[b * L_SK + l]; c += m;
                    if (m) s += skill_emb[skill_ids[b * L_SK + l] * DD + d];
                }
                v = s / (float)(c > 1 ? c : 1);
            } else if (o < 590) {
                const int d = o - 520; float s = 0.f; int c = 0;
                for (int l = 0; l < L_VS; ++l) {
                    const int m = vs_mask[b * L_VS + l]; c += m;
                    if (m) s += (d < 64) ? msite_emb[vs_ids[b * L_VS + l] * DD + d]
                                         : vs_sc[(b * L_VS + l) * SITE_SC + (d - 64)];
                }
                v = s / (float)(c > 1 ? c : 1);
            } else {
                const int d = o - 590; float s = 0.f; int c = 0;
                for (int l = 0; l < L_ME; ++l) {
                    const int m = me_mask[b * L_ME + l]; c += m;
                    if (m) s += (d < 64) ? enemy_emb[me_ids[b * L_ME + l] * DD + d]
                                         : me_sc[(b * L_ME + l) * ME_SC + (d - 64)];
                }
                v = s / (float)(c > 1 ? c : 1);
            }
            s_in[r][o] = v;
        }
    }
    __syncthreads();

    float acc[ROWS_A];
#pragma unroll
    for (int r = 0; r < ROWS_A; ++r) acc[r] = b_s[t];
    for (int k = 0; k < STATE_IN; k += 2) {
        const float w0 = W_s[k * HH + t];
        const float w1 = W_s[(k + 1) * HH + t];
#pragma unroll
        for (int r = 0; r < ROWS_A; ++r) {
            const float2 a = *(const float2*)&s_in[r][k];
            acc[r] = fmaf(a.y, w1, fmaf(a.x, w0, acc[r]));
        }
    }
#pragma unroll
    for (int r = 0; r < ROWS_A; ++r) {
        acc[r] = tanhf(acc[r]);
        s_repr[r][t] = acc[r];
    }

    const float wv = W_v[t];
    const int lane = t & 63, wid = t >> 6;
#pragma unroll
    for (int r = 0; r < ROWS_A; ++r) {
        float v = acc[r] * wv;
        for (int off = 32; off; off >>= 1) v += __shfl_down(v, off);
        if (lane == 0) s_red[r][wid] = v;
    }
    __syncthreads();
    if (t < ROWS_A) {
        out_value[b0 + t] = s_red[t][0] + s_red[t][1] + s_red[t][2] + s_red[t][3] + b_v[0];
    }

    float acc2[ROWS_A];
#pragma unroll
    for (int r = 0; r < ROWS_A; ++r) acc2[r] = 0.f;
    for (int k = 0; k < HH; k += 2) {
        const float w0 = W1[k * HH + t];
        const float w1 = W1[(k + 1) * HH + t];
#pragma unroll
        for (int r = 0; r < ROWS_A; ++r) {
            const float2 a = *(const float2*)&s_repr[r][k];
            acc2[r] = fmaf(a.y, w1, fmaf(a.x, w0, acc2[r]));
        }
    }
#pragma unroll
    for (int r = 0; r < ROWS_A; ++r) s_part[(b0 + r) * HH + t] = acc2[r];
}

// ===================== MFMA action kernel =====================
// One block per batch row b: all 64 actions, H=256 cols. 4 waves, each owns
// 64 N-columns. GEMM1: [64 x 480]@[480 x 256] bf16 MFMA; tanh; repack in LDS;
// GEMM2: [64 x 256]@[256 x 256]; fused bias/s_part/tanh/W2 reduction epilogue.
__global__ __launch_bounds__(256) void action_mfma_kernel(
    const int* __restrict__ action_ids, const float* __restrict__ action_scalars,
    const int* __restrict__ tgt_ids, const int* __restrict__ tgt_mask,
    const float* __restrict__ at_emb, const float* __restrict__ src_emb,
    const float* __restrict__ card_emb, const float* __restrict__ unit_emb,
    const float* __restrict__ enemy_emb, const float* __restrict__ skill_emb,
    const ushort* __restrict__ WaP, const float* __restrict__ b_a,
    const ushort* __restrict__ W1bP, const float* __restrict__ b1,
    const float* __restrict__ W2, const float* __restrict__ b2,
    const float* __restrict__ s_part, float* __restrict__ out_logits)
{
    __shared__ ushort sA[15 * 4 * 64 * 8];   // 30720 shorts = 61440 B (A1; A2 reuses first 32 KB)
    __shared__ float red[4][64];

    const int t = threadIdx.x;
    const int b = blockIdx.x;
    const int w = t >> 6;        // wave 0..3, owns cols w*64 .. w*64+63
    const int lane = t & 63;

    // ---- build action_input directly in packed bf16 A-fragment layout ----
    // A layout (16x16x32): m = lane&15, k = 8*(lane>>4)+e  => pack [kt][mt][lane][e]
    for (int idx = t; idx < 64 * ACT_IN; idx += 256) {
        const int m = idx / ACT_IN;
        const int k = idx - m * ACT_IN;
        const int an = b * NN + m;
        const int* ids = &action_ids[an * 6];
        float v;
        if (k < 64)       v = at_emb[ids[0] * DD + k];
        else if (k < 128) v = src_emb[ids[1] * DD + (k - 64)];
        else if (k < 192) v = card_emb[ids[2] * DD + (k - 128)];
        else if (k < 256) v = unit_emb[ids[3] * DD + (k - 192)];
        else if (k < 320) v = enemy_emb[ids[4] * DD + (k - 256)];
        else if (k < 384) v = skill_emb[ids[5] * DD + (k - 320)];
        else if (k < 448) {
            const int d = k - 384; float s = 0.f; int c = 0;
            for (int l = 0; l < L_TGT; ++l) {
                const int mk = tgt_mask[an * L_TGT + l]; c += mk;
                if (mk) s += enemy_emb[tgt_ids[an * L_TGT + l] * DD + d];
            }
            v = s / (float)(c > 1 ? c : 1);
        } else {
            v = action_scalars[an * ACT_SC + (k - 448)];
        }
        __hip_bfloat16 h = __float2bfloat16(v);
        const int pi = (((k >> 5) * 4 + (m >> 4)) * 64 +
                        ((m & 15) + 16 * ((k >> 3) & 3))) * 8 + (k & 7);
        sA[pi] = *reinterpret_cast<ushort*>(&h);
    }
    // zero the K-pad (k = 464..479)
    for (int idx = t; idx < 64 * 16; idx += 256) {
        const int m = idx >> 4;
        const int k = ACT_IN + (idx & 15);
        const int pi = ((14 * 4 + (m >> 4)) * 64 +
                        ((m & 15) + 16 * ((k >> 3) & 3))) * 8 + (k & 7);
        sA[pi] = 0;
    }
    __syncthreads();

    const short8* sA8  = (const short8*)sA;
    const short8* Wa8  = (const short8*)WaP;
    const short8* W1b8 = (const short8*)W1bP;
    const f32x4 zero = {0.f, 0.f, 0.f, 0.f};

    // ---- GEMM1: acc[mt][nt] over K=480 ----
    f32x4 acc[4][4];
#pragma unroll
    for (int i = 0; i < 4; ++i)
#pragma unroll
        for (int j = 0; j < 4; ++j) acc[i][j] = zero;

    for (int kt = 0; kt < 15; ++kt) {
        short8 a[4], bfr[4];
#pragma unroll
        for (int mt = 0; mt < 4; ++mt) a[mt] = sA8[(kt * 4 + mt) * 64 + lane];
#pragma unroll
        for (int nt = 0; nt < 4; ++nt) bfr[nt] = Wa8[(kt * 16 + w * 4 + nt) * 64 + lane];
#pragma unroll
        for (int mt = 0; mt < 4; ++mt)
#pragma unroll
            for (int nt = 0; nt < 4; ++nt)
                acc[mt][nt] = __builtin_amdgcn_mfma_f32_16x16x32_bf16(a[mt], bfr[nt], acc[mt][nt], 0, 0, 0);
    }

    __syncthreads();   // all waves done reading A1 before overwriting with A2

    // ---- epilogue 1: action_repr = tanh(acc + b_a) -> packed A2 (bf16) in sA ----
    // C/D layout: col = lane&15, row = (lane>>4)*4 + reg  [m89]
    float ba[4];
#pragma unroll
    for (int nt = 0; nt < 4; ++nt) ba[nt] = b_a[w * 64 + nt * 16 + (lane & 15)];

#pragma unroll
    for (int mt = 0; mt < 4; ++mt)
#pragma unroll
        for (int nt = 0; nt < 4; ++nt) {
            const int n = w * 64 + nt * 16 + (lane & 15);   // GEMM2 k-dim
            const int kt2 = n >> 5;
            const int lo16 = (n >> 3) & 3;
#pragma unroll
            for (int r = 0; r < 4; ++r) {
                const int m = mt * 16 + (lane >> 4) * 4 + r;
                const float h = fast_tanh(acc[mt][nt][r] + ba[nt]);
                __hip_bfloat16 hb = __float2bfloat16(h);
                const int pi = ((kt2 * 4 + mt) * 64 + ((m & 15) + 16 * lo16)) * 8 + (n & 7);
                sA[pi] = *reinterpret_cast<ushort*>(&hb);
            }
        }
    __syncthreads();

    // ---- GEMM2: over K=256 ----
#pragma unroll
    for (int i = 0; i < 4; ++i)
#pragma unroll
        for (int j = 0; j < 4; ++j) acc[i][j] = zero;

    for (int kt = 0; kt < 8; ++kt) {
        short8 a[4], bfr[4];
#pragma unroll
        for (int mt = 0; mt < 4; ++mt) a[mt] = sA8[(kt * 4 + mt) * 64 + lane];
#pragma unroll
        for (int nt = 0; nt < 4; ++nt) bfr[nt] = W1b8[(kt * 16 + w * 4 + nt) * 64 + lane];
#pragma unroll
        for (int mt = 0; mt < 4; ++mt)
#pragma unroll
            for (int nt = 0; nt < 4; ++nt)
                acc[mt][nt] = __builtin_amdgcn_mfma_f32_16x16x32_bf16(a[mt], bfr[nt], acc[mt][nt], 0, 0, 0);
    }

    // ---- epilogue 2: logits[m] = sum_n tanh(acc + s_part + b1) * W2[n] + b2 ----
    float sp[4], w2v[4];
#pragma unroll
    for (int nt = 0; nt < 4; ++nt) {
        const int n = w * 64 + nt * 16 + (lane & 15);
        sp[nt]  = s_part[b * HH + n] + b1[n];
        w2v[nt] = W2[n];
    }
    float part[4][4];
#pragma unroll
    for (int mt = 0; mt < 4; ++mt)
#pragma unroll
        for (int r = 0; r < 4; ++r) part[mt][r] = 0.f;

#pragma unroll
    for (int mt = 0; mt < 4; ++mt)
#pragma unroll
        for (int nt = 0; nt < 4; ++nt)
#pragma unroll
            for (int r = 0; r < 4; ++r)
                part[mt][r] += fast_tanh(acc[mt][nt][r] + sp[nt]) * w2v[nt];

    // reduce the 16 col-lanes of each group (rows identical across them)
#pragma unroll
    for (int mt = 0; mt < 4; ++mt)
#pragma unroll
        for (int r = 0; r < 4; ++r) {
            float v = part[mt][r];
            v += __shfl_xor(v, 1);
            v += __shfl_xor(v, 2);
            v += __shfl_xor(v, 4);
            v += __shfl_xor(v, 8);
            part[mt][r] = v;
        }
    if ((lane & 15) == 0) {
#pragma unroll
        for (int mt = 0; mt < 4; ++mt)
#pragma unroll
            for (int r = 0; r < 4; ++r) {
                const int m = mt * 16 + (lane >> 4) * 4 + r;
                red[w][m] = part[mt][r];
            }
    }
    __syncthreads();
    if (t < 64) {
        out_logits[b * NN + t] = red[0][t] + red[1][t] + red[2][t] + red[3][t] + b2[0];
    }
}

extern "C" void kernel_launch(void* const* d_in, const int* in_sizes, int n_in,
                              void* d_out, int out_size, void* d_ws, size_t ws_size,
                              hipStream_t stream) {
    const float* state_scalars = (const float*)d_in[0];
    const int*   mode_id       = (const int*)d_in[1];
    const int*   terrain_id    = (const int*)d_in[2];
    const int*   site_type_id  = (const int*)d_in[3];
    const int*   hand_ids      = (const int*)d_in[4];
    const int*   hand_mask     = (const int*)d_in[5];
    const int*   unit_ids      = (const int*)d_in[6];
    const int*   unit_mask     = (const int*)d_in[7];
    const int*   ce_ids        = (const int*)d_in[8];
    const float* ce_sc         = (const float*)d_in[9];
    const int*   ce_mask       = (const int*)d_in[10];
    const int*   skill_ids     = (const int*)d_in[11];
    const int*   skill_mask    = (const int*)d_in[12];
    const int*   vs_ids        = (const int*)d_in[13];
    const float* vs_sc         = (const float*)d_in[14];
    const int*   vs_mask       = (const int*)d_in[15];
    const int*   me_ids        = (const int*)d_in[16];
    const float* me_sc         = (const float*)d_in[17];
    const int*   me_mask       = (const int*)d_in[18];
    const int*   action_ids    = (const int*)d_in[19];
    const float* action_scalars= (const float*)d_in[20];
    const int*   tgt_ids       = (const int*)d_in[21];
    const int*   tgt_mask      = (const int*)d_in[22];
    const float* card_emb      = (const float*)d_in[23];
    const float* unit_emb      = (const float*)d_in[24];
    const float* enemy_emb     = (const float*)d_in[25];
    const float* at_emb        = (const float*)d_in[26];
    const float* src_emb       = (const float*)d_in[27];
    const float* mode_emb      = (const float*)d_in[28];
    const float* ter_emb       = (const float*)d_in[29];
    const float* site_emb      = (const float*)d_in[30];
    const float* skill_emb     = (const float*)d_in[31];
    const float* msite_emb     = (const float*)d_in[32];
    const float* W_s           = (const float*)d_in[33];
    const float* b_s           = (const float*)d_in[34];
    const float* W_a           = (const float*)d_in[35];
    const float* b_a           = (const float*)d_in[36];
    const float* W1            = (const float*)d_in[37];
    const float* b1            = (const float*)d_in[38];
    const float* W2            = (const float*)d_in[39];
    const float* b2            = (const float*)d_in[40];
    const float* W_v           = (const float*)d_in[41];
    const float* b_v           = (const float*)d_in[42];

    float* out_logits = (float*)d_out;                   // [B, N]
    float* out_value  = (float*)d_out + (size_t)BB * NN; // [B]

    // workspace layout
    float*  s_part = (float*)d_ws;                                   // 2 MB
    ushort* WaP    = (ushort*)((char*)d_ws + 2097152);               // 245,760 B
    ushort* W1bP   = (ushort*)((char*)d_ws + 2097152 + 245760);      // 131,072 B

    pack_kernel<<<(480 * 256 + 256 * 256 + 255) / 256, 256, 0, stream>>>(W_a, W1, WaP, W1bP);

    state_kernel<<<BB / ROWS_A, 256, 0, stream>>>(
        state_scalars, mode_id, terrain_id, site_type_id,
        hand_ids, hand_mask, unit_ids, unit_mask,
        ce_ids, ce_sc, ce_mask, skill_ids, skill_mask,
        vs_ids, vs_sc, vs_mask, me_ids, me_sc, me_mask,
        card_emb, unit_emb, enemy_emb, mode_emb, ter_emb, site_emb,
        skill_emb, msite_emb,
        W_s, b_s, W1, W_v, b_v, s_part, out_value);

    action_mfma_kernel<<<BB, 256, 0, stream>>>(
        action_ids, action_scalars, tgt_ids, tgt_mask,
        at_emb, src_emb, card_emb, unit_emb, enemy_emb, skill_emb,
        WaP, b_a, W1bP, b1, W2, b2, s_part, out_logits);
}

// Round 3
// 174.578 us; speedup vs baseline: 6.2107x; 2.9249x over previous
//
#include <hip/hip_runtime.h>
#include <hip/hip_bf16.h>

// ---- problem constants (match reference) ----
#define BB 2048
#define NN 64
#define DD 64
#define HH 256
#define L_HAND 16
#define L_UNIT 8
#define L_CE 8
#define L_SK 8
#define L_VS 16
#define L_ME 16
#define L_TGT 8
#define STATE_SC 64
#define CE_SC 8
#define SITE_SC 6
#define ME_SC 8
#define ACT_SC 16
#define STATE_IN 662
#define ACT_IN 464

#define ROWS_A 4   // batch rows per block in state kernel

typedef __attribute__((ext_vector_type(8))) short short8;   // 8 bf16 = 4 VGPRs
typedef __attribute__((ext_vector_type(4))) float f32x4;    // MFMA accum

__device__ __forceinline__ float fast_tanh(float x) {
    float e = __expf(2.0f * x);
    return 1.0f - 2.0f / (e + 1.0f);
}
__device__ __forceinline__ short f2bs(float x) {
    __hip_bfloat16 h = __float2bfloat16(x);
    return *reinterpret_cast<short*>(&h);
}
__device__ __forceinline__ float bs2f(short u) {
    union { unsigned int i; float f; } v;
    v.i = ((unsigned int)(unsigned short)u) << 16;
    return v.f;
}

// emb16 row offsets: at(50), src(30), card(400), unit(100), enemy(120), skill(60)
#define RO_AT    0
#define RO_SRC   50
#define RO_CARD  80
#define RO_UNIT  480
#define RO_ENEMY 580
#define RO_SKILL 700
#define EMB_ROWS 760

// ===================== weight + embedding pre-pack kernel =====================
// Packs W_a (464x256, K-padded to 480) and W1[256:,:] (256x256) into bf16 MFMA
// B-fragment layout, and converts the 6 action embedding tables to bf16 rows.
__global__ __launch_bounds__(256) void pack_kernel(
    const float* __restrict__ W_a, const float* __restrict__ W1,
    const float* __restrict__ at_emb, const float* __restrict__ src_emb,
    const float* __restrict__ card_emb, const float* __restrict__ unit_emb,
    const float* __restrict__ enemy_emb, const float* __restrict__ skill_emb,
    ushort* __restrict__ WaP, ushort* __restrict__ W1bP, ushort* __restrict__ emb16)
{
    const int idx = blockIdx.x * 256 + threadIdx.x;
    if (idx < 480 * 256) {
        const int k = idx >> 8, n = idx & 255;
        const float v = (k < ACT_IN) ? W_a[k * HH + n] : 0.f;
        const int pi = (((k >> 5) * 16 + (n >> 4)) * 64 +
                        ((n & 15) + 16 * ((k >> 3) & 3))) * 8 + (k & 7);
        WaP[pi] = (ushort)f2bs(v);
    } else if (idx < 480 * 256 + 256 * 256) {
        const int j = idx - 480 * 256;
        const int k = j >> 8, n = j & 255;
        const float v = W1[(256 + k) * HH + n];
        const int pi = (((k >> 5) * 16 + (n >> 4)) * 64 +
                        ((n & 15) + 16 * ((k >> 3) & 3))) * 8 + (k & 7);
        W1bP[pi] = (ushort)f2bs(v);
    } else {
        const int j = idx - (480 * 256 + 256 * 256);
        if (j < EMB_ROWS * 64) {
            const int row = j >> 6, d = j & 63;
            float v;
            if      (row < RO_SRC)   v = at_emb[row * 64 + d];
            else if (row < RO_CARD)  v = src_emb[(row - RO_SRC) * 64 + d];
            else if (row < RO_UNIT)  v = card_emb[(row - RO_CARD) * 64 + d];
            else if (row < RO_ENEMY) v = unit_emb[(row - RO_UNIT) * 64 + d];
            else if (row < RO_SKILL) v = enemy_emb[(row - RO_ENEMY) * 64 + d];
            else                     v = skill_emb[(row - RO_SKILL) * 64 + d];
            emb16[j] = (ushort)f2bs(v);
        }
    }
}

// ===================== state encoding kernel (fp32, unchanged) =====================
__global__ __launch_bounds__(256) void state_kernel(
    const float* __restrict__ state_scalars,
    const int* __restrict__ mode_id, const int* __restrict__ terrain_id,
    const int* __restrict__ site_type_id,
    const int* __restrict__ hand_ids, const int* __restrict__ hand_mask,
    const int* __restrict__ unit_ids, const int* __restrict__ unit_mask,
    const int* __restrict__ ce_ids, const float* __restrict__ ce_sc, const int* __restrict__ ce_mask,
    const int* __restrict__ skill_ids, const int* __restrict__ skill_mask,
    const int* __restrict__ vs_ids, const float* __restrict__ vs_sc, const int* __restrict__ vs_mask,
    const int* __restrict__ me_ids, const float* __restrict__ me_sc, const int* __restrict__ me_mask,
    const float* __restrict__ card_emb, const float* __restrict__ unit_emb,
    const float* __restrict__ enemy_emb, const float* __restrict__ mode_emb,
    const float* __restrict__ ter_emb, const float* __restrict__ site_emb,
    const float* __restrict__ skill_emb, const float* __restrict__ msite_emb,
    const float* __restrict__ W_s, const float* __restrict__ b_s,
    const float* __restrict__ W1, const float* __restrict__ W_v, const float* __restrict__ b_v,
    float* __restrict__ s_part, float* __restrict__ out_value)
{
    __shared__ float s_in[ROWS_A][STATE_IN];
    __shared__ float s_repr[ROWS_A][HH];
    __shared__ float s_red[ROWS_A][4];

    const int t = threadIdx.x;
    const int b0 = blockIdx.x * ROWS_A;

    for (int r = 0; r < ROWS_A; ++r) {
        const int b = b0 + r;
        for (int o = t; o < STATE_IN; o += 256) {
            float v;
            if (o < 64) {
                v = state_scalars[b * STATE_SC + o];
            } else if (o < 128) {
                v = mode_emb[mode_id[b] * DD + (o - 64)];
            } else if (o < 192) {
                const int d = o - 128; float s = 0.f; int c = 0;
                for (int l = 0; l < L_HAND; ++l) {
                    const int m = hand_mask[b * L_HAND + l]; c += m;
                    if (m) s += card_emb[hand_ids[b * L_HAND + l] * DD + d];
                }
                v = s / (float)(c > 1 ? c : 1);
            } else if (o < 256) {
                const int d = o - 192; float s = 0.f; int c = 0;
                for (int l = 0; l < L_UNIT; ++l) {
                    const int m = unit_mask[b * L_UNIT + l]; c += m;
                    if (m) s += unit_emb[unit_ids[b * L_UNIT + l] * DD + d];
                }
                v = s / (float)(c > 1 ? c : 1);
            } else if (o < 320) {
                v = ter_emb[terrain_id[b] * DD + (o - 256)];
            } else if (o < 384) {
                v = site_emb[site_type_id[b] * DD + (o - 320)];
            } else if (o < 456) {
                const int d = o - 384; float s = 0.f; int c = 0;
                for (int l = 0; l < L_CE; ++l) {
                    const int m = ce_mask[b * L_CE + l]; c += m;
                    if (m) s += (d < 64) ? enemy_emb[ce_ids[b * L_CE + l] * DD + d]
                                         : ce_sc[(b * L_CE + l) * CE_SC + (d - 64)];
                }
                v = s / (float)(c > 1 ? c : 1);
            } else if (o < 520) {
                const int d = o - 456; float s = 0.f; int c = 0;
                for (int l = 0; l < L_SK; ++l) {
                    const int m = skill_mask[b * L_SK + l]; c += m;
                    if (m) s += skill_emb[skill_ids[b * L_SK + l] * DD + d];
                }
                v = s / (float)(c > 1 ? c : 1);
            } else if (o < 590) {
                const int d = o - 520; float s = 0.f; int c = 0;
                for (int l = 0; l < L_VS; ++l) {
                    const int m = vs_mask[b * L_VS + l]; c += m;
                    if (m) s += (d < 64) ? msite_emb[vs_ids[b * L_VS + l] * DD + d]
                                         : vs_sc[(b * L_VS + l) * SITE_SC + (d - 64)];
                }
                v = s / (float)(c > 1 ? c : 1);
            } else {
                const int d = o - 590; float s = 0.f; int c = 0;
                for (int l = 0; l < L_ME; ++l) {
                    const int m = me_mask[b * L_ME + l]; c += m;
                    if (m) s += (d < 64) ? enemy_emb[me_ids[b * L_ME + l] * DD + d]
                                         : me_sc[(b * L_ME + l) * ME_SC + (d - 64)];
                }
                v = s / (float)(c > 1 ? c : 1);
            }
            s_in[r][o] = v;
        }
    }
    __syncthreads();

    float acc[ROWS_A];
#pragma unroll
    for (int r = 0; r < ROWS_A; ++r) acc[r] = b_s[t];
    for (int k = 0; k < STATE_IN; k += 2) {
        const float w0 = W_s[k * HH + t];
        const float w1 = W_s[(k + 1) * HH + t];
#pragma unroll
        for (int r = 0; r < ROWS_A; ++r) {
            const float2 a = *(const float2*)&s_in[r][k];
            acc[r] = fmaf(a.y, w1, fmaf(a.x, w0, acc[r]));
        }
    }
#pragma unroll
    for (int r = 0; r < ROWS_A; ++r) {
        acc[r] = tanhf(acc[r]);
        s_repr[r][t] = acc[r];
    }

    const float wv = W_v[t];
    const int lane = t & 63, wid = t >> 6;
#pragma unroll
    for (int r = 0; r < ROWS_A; ++r) {
        float v = acc[r] * wv;
        for (int off = 32; off; off >>= 1) v += __shfl_down(v, off);
        if (lane == 0) s_red[r][wid] = v;
    }
    __syncthreads();
    if (t < ROWS_A) {
        out_value[b0 + t] = s_red[t][0] + s_red[t][1] + s_red[t][2] + s_red[t][3] + b_v[0];
    }

    float acc2[ROWS_A];
#pragma unroll
    for (int r = 0; r < ROWS_A; ++r) acc2[r] = 0.f;
    for (int k = 0; k < HH; k += 2) {
        const float w0 = W1[k * HH + t];
        const float w1 = W1[(k + 1) * HH + t];
#pragma unroll
        for (int r = 0; r < ROWS_A; ++r) {
            const float2 a = *(const float2*)&s_repr[r][k];
            acc2[r] = fmaf(a.y, w1, fmaf(a.x, w0, acc2[r]));
        }
    }
#pragma unroll
    for (int r = 0; r < ROWS_A; ++r) s_part[(b0 + r) * HH + t] = acc2[r];
}

// ===================== MFMA action kernel =====================
// One block per batch row b. Builder: wave-uniform k-chunks, each thread owns
// action row m = t&63; 16B bf16 gathers from pre-converted tables; ds_write_b128
// into packed A-fragment layout. Then GEMM1 -> tanh repack -> GEMM2 -> epilogue.
__global__ __launch_bounds__(256) void action_mfma_kernel(
    const int* __restrict__ action_ids, const float* __restrict__ action_scalars,
    const int* __restrict__ tgt_ids, const int* __restrict__ tgt_mask,
    const ushort* __restrict__ emb16,
    const ushort* __restrict__ WaP, const float* __restrict__ b_a,
    const ushort* __restrict__ W1bP, const float* __restrict__ b1,
    const float* __restrict__ W2, const float* __restrict__ b2,
    const float* __restrict__ s_part, float* __restrict__ out_logits)
{
    __shared__ ushort sA[15 * 4 * 64 * 8];   // 61440 B (A1; A2 reuses first 32 KB)
    __shared__ float red[4][64];
    __shared__ int s_ids[64 * 6];
    __shared__ int s_tid[64 * 8];
    __shared__ int s_tmk[64 * 8];

    const int t = threadIdx.x;
    const int b = blockIdx.x;
    const int w = t >> 6;        // wave 0..3, owns cols w*64 .. w*64+63
    const int lane = t & 63;

    // ---- stage per-action ids / target lists in LDS (coalesced) ----
    for (int i = t; i < 64 * 6; i += 256) s_ids[i] = action_ids[b * (64 * 6) + i];
    for (int i = t; i < 64 * 8; i += 256) {
        s_tid[i] = tgt_ids[b * (64 * 8) + i];
        s_tmk[i] = tgt_mask[b * (64 * 8) + i];
    }
    __syncthreads();

    // ---- build packed A1: thread owns action row m, wave-uniform k-chunks ----
    const int m = t & 63;
    const int mt = m >> 4;
    const int mrow = m & 15;
    const int id0 = s_ids[m * 6 + 0], id1 = s_ids[m * 6 + 1], id2 = s_ids[m * 6 + 2];
    const int id3 = s_ids[m * 6 + 3], id4 = s_ids[m * 6 + 4], id5 = s_ids[m * 6 + 5];
    const ushort* enemy16 = emb16 + RO_ENEMY * 64;
    short8* sA8w = (short8*)sA;

    for (int kc = (t >> 6); kc < 60; kc += 4) {
        const int k0 = kc << 3;
        short8 val;
        if (k0 < 384) {
            int roff, id;
            const int j = k0 >> 6;
            if      (j == 0) { roff = RO_AT;    id = id0; }
            else if (j == 1) { roff = RO_SRC;   id = id1; }
            else if (j == 2) { roff = RO_CARD;  id = id2; }
            else if (j == 3) { roff = RO_UNIT;  id = id3; }
            else if (j == 4) { roff = RO_ENEMY; id = id4; }
            else             { roff = RO_SKILL; id = id5; }
            val = *(const short8*)(emb16 + (roff + id) * 64 + (k0 & 63));
        } else if (k0 < 448) {
            const int d = k0 - 384;
            float accq[8] = {0.f, 0.f, 0.f, 0.f, 0.f, 0.f, 0.f, 0.f};
            int c = 0;
#pragma unroll
            for (int l = 0; l < L_TGT; ++l) {
                const int mk = s_tmk[m * 8 + l];
                c += mk;
                const float fm = (float)mk;
                const short8 e = *(const short8*)(enemy16 + s_tid[m * 8 + l] * 64 + d);
#pragma unroll
                for (int q = 0; q < 8; ++q) accq[q] = fmaf(fm, bs2f(e[q]), accq[q]);
            }
            const float inv = 1.0f / (float)(c > 1 ? c : 1);
#pragma unroll
            for (int q = 0; q < 8; ++q) val[q] = f2bs(accq[q] * inv);
        } else if (k0 < 464) {
            const float* sc = action_scalars + (b * NN + m) * ACT_SC + (k0 - 448);
            const float4 f0 = *(const float4*)sc;
            const float4 f1 = *(const float4*)(sc + 4);
            val[0] = f2bs(f0.x); val[1] = f2bs(f0.y); val[2] = f2bs(f0.z); val[3] = f2bs(f0.w);
            val[4] = f2bs(f1.x); val[5] = f2bs(f1.y); val[6] = f2bs(f1.z); val[7] = f2bs(f1.w);
        } else {
#pragma unroll
            for (int q = 0; q < 8; ++q) val[q] = 0;
        }
        const int kt = k0 >> 5, lo = (k0 >> 3) & 3;
        sA8w[(kt * 4 + mt) * 64 + mrow + 16 * lo] = val;
    }
    __syncthreads();

    const short8* sA8  = (const short8*)sA;
    const short8* Wa8  = (const short8*)WaP;
    const short8* W1b8 = (const short8*)W1bP;
    const f32x4 zero = {0.f, 0.f, 0.f, 0.f};

    // ---- GEMM1: acc[mt][nt] over K=480 ----
    f32x4 acc[4][4];
#pragma unroll
    for (int i = 0; i < 4; ++i)
#pragma unroll
        for (int j = 0; j < 4; ++j) acc[i][j] = zero;

    for (int kt = 0; kt < 15; ++kt) {
        short8 a[4], bfr[4];
#pragma unroll
        for (int mti = 0; mti < 4; ++mti) a[mti] = sA8[(kt * 4 + mti) * 64 + lane];
#pragma unroll
        for (int nt = 0; nt < 4; ++nt) bfr[nt] = Wa8[(kt * 16 + w * 4 + nt) * 64 + lane];
#pragma unroll
        for (int mti = 0; mti < 4; ++mti)
#pragma unroll
            for (int nt = 0; nt < 4; ++nt)
                acc[mti][nt] = __builtin_amdgcn_mfma_f32_16x16x32_bf16(a[mti], bfr[nt], acc[mti][nt], 0, 0, 0);
    }

    __syncthreads();   // all waves done reading A1 before overwriting with A2

    // ---- epilogue 1: action_repr = tanh(acc + b_a) -> packed A2 (bf16) in sA ----
    // C/D layout: col = lane&15, row = (lane>>4)*4 + reg
    float ba[4];
#pragma unroll
    for (int nt = 0; nt < 4; ++nt) ba[nt] = b_a[w * 64 + nt * 16 + (lane & 15)];

#pragma unroll
    for (int mti = 0; mti < 4; ++mti)
#pragma unroll
        for (int nt = 0; nt < 4; ++nt) {
            const int n = w * 64 + nt * 16 + (lane & 15);   // GEMM2 k-dim
            const int kt2 = n >> 5;
            const int lo16 = (n >> 3) & 3;
#pragma unroll
            for (int r = 0; r < 4; ++r) {
                const int mm = mti * 16 + (lane >> 4) * 4 + r;
                const float h = fast_tanh(acc[mti][nt][r] + ba[nt]);
                const int pi = ((kt2 * 4 + mti) * 64 + ((mm & 15) + 16 * lo16)) * 8 + (n & 7);
                sA[pi] = (ushort)f2bs(h);
            }
        }
    __syncthreads();

    // ---- GEMM2: over K=256 ----
#pragma unroll
    for (int i = 0; i < 4; ++i)
#pragma unroll
        for (int j = 0; j < 4; ++j) acc[i][j] = zero;

    for (int kt = 0; kt < 8; ++kt) {
        short8 a[4], bfr[4];
#pragma unroll
        for (int mti = 0; mti < 4; ++mti) a[mti] = sA8[(kt * 4 + mti) * 64 + lane];
#pragma unroll
        for (int nt = 0; nt < 4; ++nt) bfr[nt] = W1b8[(kt * 16 + w * 4 + nt) * 64 + lane];
#pragma unroll
        for (int mti = 0; mti < 4; ++mti)
#pragma unroll
            for (int nt = 0; nt < 4; ++nt)
                acc[mti][nt] = __builtin_amdgcn_mfma_f32_16x16x32_bf16(a[mti], bfr[nt], acc[mti][nt], 0, 0, 0);
    }

    // ---- epilogue 2: logits[m] = sum_n tanh(acc + s_part + b1) * W2[n] + b2 ----
    float sp[4], w2v[4];
#pragma unroll
    for (int nt = 0; nt < 4; ++nt) {
        const int n = w * 64 + nt * 16 + (lane & 15);
        sp[nt]  = s_part[b * HH + n] + b1[n];
        w2v[nt] = W2[n];
    }
    float part[4][4];
#pragma unroll
    for (int mti = 0; mti < 4; ++mti)
#pragma unroll
        for (int r = 0; r < 4; ++r) part[mti][r] = 0.f;

#pragma unroll
    for (int mti = 0; mti < 4; ++mti)
#pragma unroll
        for (int nt = 0; nt < 4; ++nt)
#pragma unroll
            for (int r = 0; r < 4; ++r)
                part[mti][r] += fast_tanh(acc[mti][nt][r] + sp[nt]) * w2v[nt];

#pragma unroll
    for (int mti = 0; mti < 4; ++mti)
#pragma unroll
        for (int r = 0; r < 4; ++r) {
            float v = part[mti][r];
            v += __shfl_xor(v, 1);
            v += __shfl_xor(v, 2);
            v += __shfl_xor(v, 4);
            v += __shfl_xor(v, 8);
            part[mti][r] = v;
        }
    if ((lane & 15) == 0) {
#pragma unroll
        for (int mti = 0; mti < 4; ++mti)
#pragma unroll
            for (int r = 0; r < 4; ++r) {
                const int mm = mti * 16 + (lane >> 4) * 4 + r;
                red[w][mm] = part[mti][r];
            }
    }
    __syncthreads();
    if (t < 64) {
        out_logits[b * NN + t] = red[0][t] + red[1][t] + red[2][t] + red[3][t] + b2[0];
    }
}

extern "C" void kernel_launch(void* const* d_in, const int* in_sizes, int n_in,
                              void* d_out, int out_size, void* d_ws, size_t ws_size,
                              hipStream_t stream) {
    const float* state_scalars = (const float*)d_in[0];
    const int*   mode_id       = (const int*)d_in[1];
    const int*   terrain_id    = (const int*)d_in[2];
    const int*   site_type_id  = (const int*)d_in[3];
    const int*   hand_ids      = (const int*)d_in[4];
    const int*   hand_mask     = (const int*)d_in[5];
    const int*   unit_ids      = (const int*)d_in[6];
    const int*   unit_mask     = (const int*)d_in[7];
    const int*   ce_ids        = (const int*)d_in[8];
    const float* ce_sc         = (const float*)d_in[9];
    const int*   ce_mask       = (const int*)d_in[10];
    const int*   skill_ids     = (const int*)d_in[11];
    const int*   skill_mask    = (const int*)d_in[12];
    const int*   vs_ids        = (const int*)d_in[13];
    const float* vs_sc         = (const float*)d_in[14];
    const int*   vs_mask       = (const int*)d_in[15];
    const int*   me_ids        = (const int*)d_in[16];
    const float* me_sc         = (const float*)d_in[17];
    const int*   me_mask       = (const int*)d_in[18];
    const int*   action_ids    = (const int*)d_in[19];
    const float* action_scalars= (const float*)d_in[20];
    const int*   tgt_ids       = (const int*)d_in[21];
    const int*   tgt_mask      = (const int*)d_in[22];
    const float* card_emb      = (const float*)d_in[23];
    const float* unit_emb      = (const float*)d_in[24];
    const float* enemy_emb     = (const float*)d_in[25];
    const float* at_emb        = (const float*)d_in[26];
    const float* src_emb       = (const float*)d_in[27];
    const float* mode_emb      = (const float*)d_in[28];
    const float* ter_emb       = (const float*)d_in[29];
    const float* site_emb      = (const float*)d_in[30];
    const float* skill_emb     = (const float*)d_in[31];
    const float* msite_emb     = (const float*)d_in[32];
    const float* W_s           = (const float*)d_in[33];
    const float* b_s           = (const float*)d_in[34];
    const float* W_a           = (const float*)d_in[35];
    const float* b_a           = (const float*)d_in[36];
    const float* W1            = (const float*)d_in[37];
    const float* b1            = (const float*)d_in[38];
    const float* W2            = (const float*)d_in[39];
    const float* b2            = (const float*)d_in[40];
    const float* W_v           = (const float*)d_in[41];
    const float* b_v           = (const float*)d_in[42];

    float* out_logits = (float*)d_out;                   // [B, N]
    float* out_value  = (float*)d_out + (size_t)BB * NN; // [B]

    // workspace layout (16B-aligned sections)
    float*  s_part = (float*)d_ws;                                       // 2,097,152 B
    ushort* WaP    = (ushort*)((char*)d_ws + 2097152);                   // 245,760 B
    ushort* W1bP   = (ushort*)((char*)d_ws + 2097152 + 245760);          // 131,072 B
    ushort* emb16  = (ushort*)((char*)d_ws + 2097152 + 245760 + 131072); // 97,280 B

    const int pack_total = 480 * 256 + 256 * 256 + EMB_ROWS * 64;
    pack_kernel<<<(pack_total + 255) / 256, 256, 0, stream>>>(
        W_a, W1, at_emb, src_emb, card_emb, unit_emb, enemy_emb, skill_emb,
        WaP, W1bP, emb16);

    state_kernel<<<BB / ROWS_A, 256, 0, stream>>>(
        state_scalars, mode_id, terrain_id, site_type_id,
        hand_ids, hand_mask, unit_ids, unit_mask,
        ce_ids, ce_sc, ce_mask, skill_ids, skill_mask,
        vs_ids, vs_sc, vs_mask, me_ids, me_sc, me_mask,
        card_emb, unit_emb, enemy_emb, mode_emb, ter_emb, site_emb,
        skill_emb, msite_emb,
        W_s, b_s, W1, W_v, b_v, s_part, out_value);

    action_mfma_kernel<<<BB, 256, 0, stream>>>(
        action_ids, action_scalars, tgt_ids, tgt_mask,
        emb16, WaP, b_a, W1bP, b1, W2, b2, s_part, out_logits);
}

// Round 4
// 170.830 us; speedup vs baseline: 6.3470x; 1.0219x over previous
//
#include <hip/hip_runtime.h>
#include <hip/hip_bf16.h>

// ---- problem constants (match reference) ----
#define BB 2048
#define NN 64
#define DD 64
#define HH 256
#define L_HAND 16
#define L_UNIT 8
#define L_CE 8
#define L_SK 8
#define L_VS 16
#define L_ME 16
#define L_TGT 8
#define STATE_SC 64
#define CE_SC 8
#define SITE_SC 6
#define ME_SC 8
#define ACT_SC 16
#define STATE_IN 662
#define ACT_IN 464

#define SROWS 4      // batch rows per block in state kernel
#define SK 672       // state K padded to 21*32
#define SSTRIDE 676  // fp32 LDS row stride (16B aligned, breaks worst conflicts)

typedef __attribute__((ext_vector_type(8))) short short8;   // 8 bf16 = 4 VGPRs
typedef __attribute__((ext_vector_type(4))) float f32x4;    // MFMA accum

__device__ __forceinline__ float fast_tanh(float x) {
    float e = __expf(2.0f * x);
    return 1.0f - 2.0f / (e + 1.0f);
}
__device__ __forceinline__ short f2bs(float x) {
    __hip_bfloat16 h = __float2bfloat16(x);
    return *reinterpret_cast<short*>(&h);
}
__device__ __forceinline__ float bs2f(short u) {
    union { unsigned int i; float f; } v;
    v.i = ((unsigned int)(unsigned short)u) << 16;
    return v.f;
}

// emb16 row offsets: at(50), src(30), card(400), unit(100), enemy(120), skill(60)
#define RO_AT    0
#define RO_SRC   50
#define RO_CARD  80
#define RO_UNIT  480
#define RO_ENEMY 580
#define RO_SKILL 700
#define EMB_ROWS 760

// pack segment boundaries
#define T0 (480 * 256)            // WaP
#define T1 (T0 + 256 * 256)       // W1bP
#define T2 (T1 + EMB_ROWS * 64)   // emb16
#define T3 (T2 + SK * 256)        // WsP
#define T4 (T3 + 256 * 256)       // W1aP

// ===================== weight + embedding pre-pack kernel =====================
__global__ __launch_bounds__(256) void pack_kernel(
    const float* __restrict__ W_a, const float* __restrict__ W1,
    const float* __restrict__ W_s,
    const float* __restrict__ at_emb, const float* __restrict__ src_emb,
    const float* __restrict__ card_emb, const float* __restrict__ unit_emb,
    const float* __restrict__ enemy_emb, const float* __restrict__ skill_emb,
    ushort* __restrict__ WaP, ushort* __restrict__ W1bP, ushort* __restrict__ emb16,
    ushort* __restrict__ WsP, ushort* __restrict__ W1aP)
{
    const int idx = blockIdx.x * 256 + threadIdx.x;
    if (idx < T0) {
        const int k = idx >> 8, n = idx & 255;
        const float v = (k < ACT_IN) ? W_a[k * HH + n] : 0.f;
        const int pi = (((k >> 5) * 16 + (n >> 4)) * 64 +
                        ((n & 15) + 16 * ((k >> 3) & 3))) * 8 + (k & 7);
        WaP[pi] = (ushort)f2bs(v);
    } else if (idx < T1) {
        const int j = idx - T0;
        const int k = j >> 8, n = j & 255;
        const float v = W1[(256 + k) * HH + n];
        const int pi = (((k >> 5) * 16 + (n >> 4)) * 64 +
                        ((n & 15) + 16 * ((k >> 3) & 3))) * 8 + (k & 7);
        W1bP[pi] = (ushort)f2bs(v);
    } else if (idx < T2) {
        const int j = idx - T1;
        const int row = j >> 6, d = j & 63;
        float v;
        if      (row < RO_SRC)   v = at_emb[row * 64 + d];
        else if (row < RO_CARD)  v = src_emb[(row - RO_SRC) * 64 + d];
        else if (row < RO_UNIT)  v = card_emb[(row - RO_CARD) * 64 + d];
        else if (row < RO_ENEMY) v = unit_emb[(row - RO_UNIT) * 64 + d];
        else if (row < RO_SKILL) v = enemy_emb[(row - RO_ENEMY) * 64 + d];
        else                     v = skill_emb[(row - RO_SKILL) * 64 + d];
        emb16[j] = (ushort)f2bs(v);
    } else if (idx < T3) {
        const int j = idx - T2;
        const int k = j >> 8, n = j & 255;
        const float v = (k < STATE_IN) ? W_s[k * HH + n] : 0.f;
        const int pi = (((k >> 5) * 16 + (n >> 4)) * 64 +
                        ((n & 15) + 16 * ((k >> 3) & 3))) * 8 + (k & 7);
        WsP[pi] = (ushort)f2bs(v);
    } else if (idx < T4) {
        const int j = idx - T3;
        const int k = j >> 8, n = j & 255;
        const float v = W1[k * HH + n];   // first (state) half of W1
        const int pi = (((k >> 5) * 16 + (n >> 4)) * 64 +
                        ((n & 15) + 16 * ((k >> 3) & 3))) * 8 + (k & 7);
        W1aP[pi] = (ushort)f2bs(v);
    }
}

// ===================== state encoding kernel (MFMA) =====================
// 512 blocks x 256 threads, SROWS=4 batch rows per block. fp32 builder into
// LDS, bf16 MFMA over K=672 (tanh fused) -> value head + in-LDS A2 repack ->
// MFMA over K=256 -> s_part (fp32).
__global__ __launch_bounds__(256) void state_mfma_kernel(
    const float* __restrict__ state_scalars,
    const int* __restrict__ mode_id, const int* __restrict__ terrain_id,
    const int* __restrict__ site_type_id,
    const int* __restrict__ hand_ids, const int* __restrict__ hand_mask,
    const int* __restrict__ unit_ids, const int* __restrict__ unit_mask,
    const int* __restrict__ ce_ids, const float* __restrict__ ce_sc, const int* __restrict__ ce_mask,
    const int* __restrict__ skill_ids, const int* __restrict__ skill_mask,
    const int* __restrict__ vs_ids, const float* __restrict__ vs_sc, const int* __restrict__ vs_mask,
    const int* __restrict__ me_ids, const float* __restrict__ me_sc, const int* __restrict__ me_mask,
    const float* __restrict__ card_emb, const float* __restrict__ unit_emb,
    const float* __restrict__ enemy_emb, const float* __restrict__ mode_emb,
    const float* __restrict__ ter_emb, const float* __restrict__ site_emb,
    const float* __restrict__ skill_emb, const float* __restrict__ msite_emb,
    const ushort* __restrict__ WsP, const float* __restrict__ b_s,
    const ushort* __restrict__ W1aP,
    const float* __restrict__ W_v, const float* __restrict__ b_v,
    float* __restrict__ s_part, float* __restrict__ out_value)
{
    __shared__ float s_in[SROWS * SSTRIDE];   // 10,816 B
    __shared__ ushort sA2[8 * 64 * 8];        // 8,192 B (GEMM2 A, bf16 packed)
    __shared__ float red[4][4];

    const int t = threadIdx.x;
    const int b0 = blockIdx.x * SROWS;
    const int w = t >> 6;
    const int lane = t & 63;

    // ---- fp32 builder (per-element, pools) ----
    for (int r = 0; r < SROWS; ++r) {
        const int b = b0 + r;
        for (int o = t; o < SK; o += 256) {
            float v;
            if (o >= STATE_IN) {
                v = 0.f;
            } else if (o < 64) {
                v = state_scalars[b * STATE_SC + o];
            } else if (o < 128) {
                v = mode_emb[mode_id[b] * DD + (o - 64)];
            } else if (o < 192) {
                const int d = o - 128; float s = 0.f; int c = 0;
                for (int l = 0; l < L_HAND; ++l) {
                    const int m = hand_mask[b * L_HAND + l]; c += m;
                    if (m) s += card_emb[hand_ids[b * L_HAND + l] * DD + d];
                }
                v = s / (float)(c > 1 ? c : 1);
            } else if (o < 256) {
                const int d = o - 192; float s = 0.f; int c = 0;
                for (int l = 0; l < L_UNIT; ++l) {
                    const int m = unit_mask[b * L_UNIT + l]; c += m;
                    if (m) s += unit_emb[unit_ids[b * L_UNIT + l] * DD + d];
                }
                v = s / (float)(c > 1 ? c : 1);
            } else if (o < 320) {
                v = ter_emb[terrain_id[b] * DD + (o - 256)];
            } else if (o < 384) {
                v = site_emb[site_type_id[b] * DD + (o - 320)];
            } else if (o < 456) {
                const int d = o - 384; float s = 0.f; int c = 0;
                for (int l = 0; l < L_CE; ++l) {
                    const int m = ce_mask[b * L_CE + l]; c += m;
                    if (m) s += (d < 64) ? enemy_emb[ce_ids[b * L_CE + l] * DD + d]
                                         : ce_sc[(b * L_CE + l) * CE_SC + (d - 64)];
                }
                v = s / (float)(c > 1 ? c : 1);
            } else if (o < 520) {
                const int d = o - 456; float s = 0.f; int c = 0;
                for (int l = 0; l < L_SK; ++l) {
                    const int m = skill_mask[b * L_SK + l]; c += m;
                    if (m) s += skill_emb[skill_ids[b * L_SK + l] * DD + d];
                }
                v = s / (float)(c > 1 ? c : 1);
            } else if (o < 590) {
                const int d = o - 520; float s = 0.f; int c = 0;
                for (int l = 0; l < L_VS; ++l) {
                    const int m = vs_mask[b * L_VS + l]; c += m;
                    if (m) s += (d < 64) ? msite_emb[vs_ids[b * L_VS + l] * DD + d]
                                         : vs_sc[(b * L_VS + l) * SITE_SC + (d - 64)];
                }
                v = s / (float)(c > 1 ? c : 1);
            } else {
                const int d = o - 590; float s = 0.f; int c = 0;
                for (int l = 0; l < L_ME; ++l) {
                    const int m = me_mask[b * L_ME + l]; c += m;
                    if (m) s += (d < 64) ? enemy_emb[me_ids[b * L_ME + l] * DD + d]
                                         : me_sc[(b * L_ME + l) * ME_SC + (d - 64)];
                }
                v = s / (float)(c > 1 ? c : 1);
            }
            s_in[r * SSTRIDE + o] = v;
        }
    }
    __syncthreads();

    const short8* Ws8  = (const short8*)WsP;
    const short8* W1a8 = (const short8*)W1aP;
    const f32x4 zero = {0.f, 0.f, 0.f, 0.f};
    const int m15 = lane & 15;
    const int g = lane >> 4;
    // duplicate rows: lanes with m15>=4 re-read row m15&3 (keeps reads in-bounds;
    // resulting C rows 4..15 are duplicates, never stored)
    const float* arow = s_in + (m15 & 3) * SSTRIDE;

    // ---- GEMM1: state_input @ W_s over K=672 ----
    f32x4 acc1[4];
#pragma unroll
    for (int nt = 0; nt < 4; ++nt) acc1[nt] = zero;

    for (int kt = 0; kt < 21; ++kt) {
        const int k0 = kt * 32 + 8 * g;
        const float4 v0 = *(const float4*)(arow + k0);
        const float4 v1 = *(const float4*)(arow + k0 + 4);
        short8 a;
        a[0] = f2bs(v0.x); a[1] = f2bs(v0.y); a[2] = f2bs(v0.z); a[3] = f2bs(v0.w);
        a[4] = f2bs(v1.x); a[5] = f2bs(v1.y); a[6] = f2bs(v1.z); a[7] = f2bs(v1.w);
        short8 bfr[4];
#pragma unroll
        for (int nt = 0; nt < 4; ++nt) bfr[nt] = Ws8[(kt * 16 + w * 4 + nt) * 64 + lane];
#pragma unroll
        for (int nt = 0; nt < 4; ++nt)
            acc1[nt] = __builtin_amdgcn_mfma_f32_16x16x32_bf16(a, bfr[nt], acc1[nt], 0, 0, 0);
    }

    // ---- epilogue: tanh, value partials, A2 pack (valid rows = lanes 0..15) ----
    float sr[4][4];
    float pv[4] = {0.f, 0.f, 0.f, 0.f};
#pragma unroll
    for (int nt = 0; nt < 4; ++nt) {
        const int n = w * 64 + nt * 16 + m15;
        const float bsn = b_s[n];
        const float wvn = W_v[n];
#pragma unroll
        for (int r = 0; r < 4; ++r) {
            const float sv = fast_tanh(acc1[nt][r] + bsn);
            sr[nt][r] = sv;
            pv[r] = fmaf(sv, wvn, pv[r]);
        }
    }
#pragma unroll
    for (int r = 0; r < 4; ++r) {
        float v = pv[r];
        v += __shfl_xor(v, 1);
        v += __shfl_xor(v, 2);
        v += __shfl_xor(v, 4);
        v += __shfl_xor(v, 8);
        if (lane == 0) red[w][r] = v;
    }
    if (g == 0) {   // lanes 0..15 hold the 4 real rows (m = r)
#pragma unroll
        for (int nt = 0; nt < 4; ++nt) {
            const int n = w * 64 + nt * 16 + m15;   // GEMM2 k-dim
            const int kt2 = n >> 5;
            const int lo16 = (n >> 3) & 3;
#pragma unroll
            for (int r = 0; r < 4; ++r) {
                const int pi = (kt2 * 64 + (r + 16 * lo16)) * 8 + (n & 7);
                sA2[pi] = (ushort)f2bs(sr[nt][r]);
            }
        }
    }
    __syncthreads();

    if (t < SROWS) {
        out_value[b0 + t] = red[0][t] + red[1][t] + red[2][t] + red[3][t] + b_v[0];
    }

    // ---- GEMM2: state_repr @ W1[:256,:] over K=256 -> s_part fp32 ----
    const short8* sA2_8 = (const short8*)sA2;
    f32x4 acc2[4];
#pragma unroll
    for (int nt = 0; nt < 4; ++nt) acc2[nt] = zero;
#pragma unroll
    for (int kt = 0; kt < 8; ++kt) {
        const short8 a2 = sA2_8[kt * 64 + lane];
        short8 bfr[4];
#pragma unroll
        for (int nt = 0; nt < 4; ++nt) bfr[nt] = W1a8[(kt * 16 + w * 4 + nt) * 64 + lane];
#pragma unroll
        for (int nt = 0; nt < 4; ++nt)
            acc2[nt] = __builtin_amdgcn_mfma_f32_16x16x32_bf16(a2, bfr[nt], acc2[nt], 0, 0, 0);
    }
    if (g == 0) {
#pragma unroll
        for (int nt = 0; nt < 4; ++nt) {
            const int n = w * 64 + nt * 16 + m15;
#pragma unroll
            for (int r = 0; r < 4; ++r)
                s_part[(b0 + r) * HH + n] = acc2[nt][r];
        }
    }
}

// ===================== MFMA action kernel =====================
// One block per batch row. GEMM1 A-fragments for k<384 gathered DIRECTLY from
// bf16 tables (no LDS staging); only tgt_pool+scalars tail (k=384..480) staged.
// A2 (32 KB) reuses the same LDS. 4 blocks/CU.
__global__ __launch_bounds__(256, 4) void action_mfma_kernel(
    const int* __restrict__ action_ids, const float* __restrict__ action_scalars,
    const int* __restrict__ tgt_ids, const int* __restrict__ tgt_mask,
    const ushort* __restrict__ emb16,
    const ushort* __restrict__ WaP, const float* __restrict__ b_a,
    const ushort* __restrict__ W1bP, const float* __restrict__ b1,
    const float* __restrict__ W2, const float* __restrict__ b2,
    const float* __restrict__ s_part, float* __restrict__ out_logits)
{
    __shared__ ushort sA[8 * 4 * 64 * 8];  // 32,768 B: tail A1 (12 KB) then A2
    __shared__ float red[4][64];
    __shared__ int s_ids[64 * 6];
    __shared__ int s_tid[64 * 8];
    __shared__ int s_tmk[64 * 8];

    const int t = threadIdx.x;
    const int b = blockIdx.x;
    const int w = t >> 6;        // wave 0..3, owns cols w*64 .. w*64+63
    const int lane = t & 63;

    // ---- stage ids / target lists (coalesced) ----
    for (int i = t; i < 64 * 6; i += 256) s_ids[i] = action_ids[b * (64 * 6) + i];
    for (int i = t; i < 64 * 8; i += 256) {
        s_tid[i] = tgt_ids[b * (64 * 8) + i];
        s_tmk[i] = tgt_mask[b * (64 * 8) + i];
    }
    __syncthreads();

    // ---- build packed A1 TAIL only (k = 384..480): tgt_pool, scalars, pad ----
    {
        const int m = lane;
        const int mt = m >> 4;
        const int mrow = m & 15;
        const ushort* enemy16 = emb16 + RO_ENEMY * 64;
        short8* sA8w = (short8*)sA;
        for (int kc = 48 + w; kc < 60; kc += 4) {
            const int k0 = kc << 3;
            short8 val;
            if (k0 < 448) {
                const int d = k0 - 384;
                float accq[8] = {0.f, 0.f, 0.f, 0.f, 0.f, 0.f, 0.f, 0.f};
                int c = 0;
#pragma unroll
                for (int l = 0; l < L_TGT; ++l) {
                    const int mk = s_tmk[m * 8 + l];
                    c += mk;
                    const float fm = (float)mk;
                    const short8 e = *(const short8*)(enemy16 + s_tid[m * 8 + l] * 64 + d);
#pragma unroll
                    for (int q = 0; q < 8; ++q) accq[q] = fmaf(fm, bs2f(e[q]), accq[q]);
                }
                const float inv = 1.0f / (float)(c > 1 ? c : 1);
#pragma unroll
                for (int q = 0; q < 8; ++q) val[q] = f2bs(accq[q] * inv);
            } else if (k0 < 464) {
                const float* sc = action_scalars + (b * NN + m) * ACT_SC + (k0 - 448);
                const float4 f0 = *(const float4*)sc;
                const float4 f1 = *(const float4*)(sc + 4);
                val[0] = f2bs(f0.x); val[1] = f2bs(f0.y); val[2] = f2bs(f0.z); val[3] = f2bs(f0.w);
                val[4] = f2bs(f1.x); val[5] = f2bs(f1.y); val[6] = f2bs(f1.z); val[7] = f2bs(f1.w);
            } else {
#pragma unroll
                for (int q = 0; q < 8; ++q) val[q] = 0;
            }
            const int kt_local = (k0 >> 5) - 12;        // 0..2
            const int lo = (k0 >> 3) & 3;
            sA8w[(kt_local * 4 + mt) * 64 + mrow + 16 * lo] = val;
        }
    }
    __syncthreads();

    const short8* sA8  = (const short8*)sA;
    const short8* Wa8  = (const short8*)WaP;
    const short8* W1b8 = (const short8*)W1bP;
    const f32x4 zero = {0.f, 0.f, 0.f, 0.f};
    const int m15 = lane & 15;
    const int koffbase = 8 * (lane >> 4);
    const int ROFFS[6] = {RO_AT, RO_SRC, RO_CARD, RO_UNIT, RO_ENEMY, RO_SKILL};

    // ---- GEMM1: K=480; kt 0..11 direct-gather, kt 12..14 from LDS tail ----
    f32x4 acc[4][4];
#pragma unroll
    for (int i = 0; i < 4; ++i)
#pragma unroll
        for (int j = 0; j < 4; ++j) acc[i][j] = zero;

#pragma unroll
    for (int kt = 0; kt < 12; ++kt) {
        const int j = kt >> 1;                          // wave-uniform, folds
        const int koff = ((kt & 1) << 5) + koffbase;
        short8 a[4], bfr[4];
#pragma unroll
        for (int mti = 0; mti < 4; ++mti) {
            const int id = s_ids[(mti * 16 + m15) * 6 + j];
            a[mti] = *(const short8*)(emb16 + (ROFFS[j] + id) * 64 + koff);
        }
#pragma unroll
        for (int nt = 0; nt < 4; ++nt) bfr[nt] = Wa8[(kt * 16 + w * 4 + nt) * 64 + lane];
#pragma unroll
        for (int mti = 0; mti < 4; ++mti)
#pragma unroll
            for (int nt = 0; nt < 4; ++nt)
                acc[mti][nt] = __builtin_amdgcn_mfma_f32_16x16x32_bf16(a[mti], bfr[nt], acc[mti][nt], 0, 0, 0);
    }
#pragma unroll
    for (int kt = 12; kt < 15; ++kt) {
        short8 a[4], bfr[4];
#pragma unroll
        for (int mti = 0; mti < 4; ++mti) a[mti] = sA8[((kt - 12) * 4 + mti) * 64 + lane];
#pragma unroll
        for (int nt = 0; nt < 4; ++nt) bfr[nt] = Wa8[(kt * 16 + w * 4 + nt) * 64 + lane];
#pragma unroll
        for (int mti = 0; mti < 4; ++mti)
#pragma unroll
            for (int nt = 0; nt < 4; ++nt)
                acc[mti][nt] = __builtin_amdgcn_mfma_f32_16x16x32_bf16(a[mti], bfr[nt], acc[mti][nt], 0, 0, 0);
    }

    __syncthreads();   // all waves done reading A1 tail before writing A2

    // ---- epilogue 1: action_repr = tanh(acc + b_a) -> packed A2 in sA ----
    float ba[4];
#pragma unroll
    for (int nt = 0; nt < 4; ++nt) ba[nt] = b_a[w * 64 + nt * 16 + m15];

#pragma unroll
    for (int mti = 0; mti < 4; ++mti)
#pragma unroll
        for (int nt = 0; nt < 4; ++nt) {
            const int n = w * 64 + nt * 16 + m15;       // GEMM2 k-dim
            const int kt2 = n >> 5;
            const int lo16 = (n >> 3) & 3;
#pragma unroll
            for (int r = 0; r < 4; ++r) {
                const int mm = mti * 16 + (lane >> 4) * 4 + r;
                const float h = fast_tanh(acc[mti][nt][r] + ba[nt]);
                const int pi = ((kt2 * 4 + mti) * 64 + ((mm & 15) + 16 * lo16)) * 8 + (n & 7);
                sA[pi] = (ushort)f2bs(h);
            }
        }
    __syncthreads();

    // ---- GEMM2: over K=256 ----
#pragma unroll
    for (int i = 0; i < 4; ++i)
#pragma unroll
        for (int j = 0; j < 4; ++j) acc[i][j] = zero;

#pragma unroll
    for (int kt = 0; kt < 8; ++kt) {
        short8 a[4], bfr[4];
#pragma unroll
        for (int mti = 0; mti < 4; ++mti) a[mti] = sA8[(kt * 4 + mti) * 64 + lane];
#pragma unroll
        for (int nt = 0; nt < 4; ++nt) bfr[nt] = W1b8[(kt * 16 + w * 4 + nt) * 64 + lane];
#pragma unroll
        for (int mti = 0; mti < 4; ++mti)
#pragma unroll
            for (int nt = 0; nt < 4; ++nt)
                acc[mti][nt] = __builtin_amdgcn_mfma_f32_16x16x32_bf16(a[mti], bfr[nt], acc[mti][nt], 0, 0, 0);
    }

    // ---- epilogue 2: logits[m] = sum_n tanh(acc + s_part + b1) * W2[n] + b2 ----
    float sp[4], w2v[4];
#pragma unroll
    for (int nt = 0; nt < 4; ++nt) {
        const int n = w * 64 + nt * 16 + m15;
        sp[nt]  = s_part[b * HH + n] + b1[n];
        w2v[nt] = W2[n];
    }
    float part[4][4];
#pragma unroll
    for (int mti = 0; mti < 4; ++mti)
#pragma unroll
        for (int r = 0; r < 4; ++r) part[mti][r] = 0.f;

#pragma unroll
    for (int mti = 0; mti < 4; ++mti)
#pragma unroll
        for (int nt = 0; nt < 4; ++nt)
#pragma unroll
            for (int r = 0; r < 4; ++r)
                part[mti][r] += fast_tanh(acc[mti][nt][r] + sp[nt]) * w2v[nt];

#pragma unroll
    for (int mti = 0; mti < 4; ++mti)
#pragma unroll
        for (int r = 0; r < 4; ++r) {
            float v = part[mti][r];
            v += __shfl_xor(v, 1);
            v += __shfl_xor(v, 2);
            v += __shfl_xor(v, 4);
            v += __shfl_xor(v, 8);
            part[mti][r] = v;
        }
    if (m15 == 0) {
#pragma unroll
        for (int mti = 0; mti < 4; ++mti)
#pragma unroll
            for (int r = 0; r < 4; ++r) {
                const int mm = mti * 16 + (lane >> 4) * 4 + r;
                red[w][mm] = part[mti][r];
            }
    }
    __syncthreads();
    if (t < 64) {
        out_logits[b * NN + t] = red[0][t] + red[1][t] + red[2][t] + red[3][t] + b2[0];
    }
}

extern "C" void kernel_launch(void* const* d_in, const int* in_sizes, int n_in,
                              void* d_out, int out_size, void* d_ws, size_t ws_size,
                              hipStream_t stream) {
    const float* state_scalars = (const float*)d_in[0];
    const int*   mode_id       = (const int*)d_in[1];
    const int*   terrain_id    = (const int*)d_in[2];
    const int*   site_type_id  = (const int*)d_in[3];
    const int*   hand_ids      = (const int*)d_in[4];
    const int*   hand_mask     = (const int*)d_in[5];
    const int*   unit_ids      = (const int*)d_in[6];
    const int*   unit_mask     = (const int*)d_in[7];
    const int*   ce_ids        = (const int*)d_in[8];
    const float* ce_sc         = (const float*)d_in[9];
    const int*   ce_mask       = (const int*)d_in[10];
    const int*   skill_ids     = (const int*)d_in[11];
    const int*   skill_mask    = (const int*)d_in[12];
    const int*   vs_ids        = (const int*)d_in[13];
    const float* vs_sc         = (const float*)d_in[14];
    const int*   vs_mask       = (const int*)d_in[15];
    const int*   me_ids        = (const int*)d_in[16];
    const float* me_sc         = (const float*)d_in[17];
    const int*   me_mask       = (const int*)d_in[18];
    const int*   action_ids    = (const int*)d_in[19];
    const float* action_scalars= (const float*)d_in[20];
    const int*   tgt_ids       = (const int*)d_in[21];
    const int*   tgt_mask      = (const int*)d_in[22];
    const float* card_emb      = (const float*)d_in[23];
    const float* unit_emb      = (const float*)d_in[24];
    const float* enemy_emb     = (const float*)d_in[25];
    const float* at_emb        = (const float*)d_in[26];
    const float* src_emb       = (const float*)d_in[27];
    const float* mode_emb      = (const float*)d_in[28];
    const float* ter_emb       = (const float*)d_in[29];
    const float* site_emb      = (const float*)d_in[30];
    const float* skill_emb     = (const float*)d_in[31];
    const float* msite_emb     = (const float*)d_in[32];
    const float* W_s           = (const float*)d_in[33];
    const float* b_s           = (const float*)d_in[34];
    const float* W_a           = (const float*)d_in[35];
    const float* b_a           = (const float*)d_in[36];
    const float* W1            = (const float*)d_in[37];
    const float* b1            = (const float*)d_in[38];
    const float* W2            = (const float*)d_in[39];
    const float* b2            = (const float*)d_in[40];
    const float* W_v           = (const float*)d_in[41];
    const float* b_v           = (const float*)d_in[42];

    float* out_logits = (float*)d_out;                   // [B, N]
    float* out_value  = (float*)d_out + (size_t)BB * NN; // [B]

    // workspace layout (16B-aligned sections)
    char* ws = (char*)d_ws;
    float*  s_part = (float*)ws;                          // 2,097,152 B
    ushort* WaP    = (ushort*)(ws + 2097152);             // 245,760 B
    ushort* W1bP   = (ushort*)(ws + 2342912);             // 131,072 B
    ushort* emb16  = (ushort*)(ws + 2473984);             //  97,280 B
    ushort* WsP    = (ushort*)(ws + 2571264);             // 344,064 B
    ushort* W1aP   = (ushort*)(ws + 2915328);             // 131,072 B (end 3,046,400)

    pack_kernel<<<(T4 + 255) / 256, 256, 0, stream>>>(
        W_a, W1, W_s, at_emb, src_emb, card_emb, unit_emb, enemy_emb, skill_emb,
        WaP, W1bP, emb16, WsP, W1aP);

    state_mfma_kernel<<<BB / SROWS, 256, 0, stream>>>(
        state_scalars, mode_id, terrain_id, site_type_id,
        hand_ids, hand_mask, unit_ids, unit_mask,
        ce_ids, ce_sc, ce_mask, skill_ids, skill_mask,
        vs_ids, vs_sc, vs_mask, me_ids, me_sc, me_mask,
        card_emb, unit_emb, enemy_emb, mode_emb, ter_emb, site_emb,
        skill_emb, msite_emb,
        WsP, b_s, W1aP, W_v, b_v, s_part, out_value);

    action_mfma_kernel<<<BB, 256, 0, stream>>>(
        action_ids, action_scalars, tgt_ids, tgt_mask,
        emb16, WaP, b_a, W1bP, b1, W2, b2, s_part, out_logits);
}